// Round 14
// baseline (467.106 us; speedup 1.0000x reference)
//
#include <hip/hip_runtime.h>

#define BB 8
#define LL 32768
#define DD 64

typedef float f4 __attribute__((ext_vector_type(4)));

// ws layout:
// [0, 256K)        : double part[BB][CHUNKS_Q][DD]  (fully written by k1)
// [256K, 2.25M)    : double scores[BB*LL]
// [0x240000]       : u32 ghist[BB][4096]  (128KB, zeroed by k1 blocks 0..127)
// [0x260000]       : u64 gAnd[8]; [0x260040] u64 gOr[8]; [0x260080] u32 eqCnt[8]
// [0x260100]       : u64 eqKey[BB][ECAP]; then u32 eqIdx[BB][ECAP]

#define OUT_F4 (BB * LL * DD / 4)
#define CHUNKS_Q 64
#define ROWS_Q (LL / CHUNKS_Q)
#define ECAP 2048
#define MAXSEL 96

// ---------------- Kernel 1: per-chunk partials + zero-fill + ws init ----------------
__global__ __launch_bounds__(256) void k_reduce_q(const float* __restrict__ q,
                                                  double* __restrict__ part,
                                                  float* __restrict__ out,
                                                  unsigned int* __restrict__ ghist,
                                                  unsigned long long* __restrict__ gAnd,
                                                  unsigned long long* __restrict__ gOr,
                                                  unsigned int* __restrict__ eqCnt) {
    if (blockIdx.x < 128) ghist[blockIdx.x * 256 + threadIdx.x] = 0;
    if (blockIdx.x == 128 && threadIdx.x < BB) {
        gAnd[threadIdx.x] = ~0ULL; gOr[threadIdx.x] = 0ULL; eqCnt[threadIdx.x] = 0u;
    }
    {
        f4 z = (f4)(0.0f);
        f4* oz = (f4*)out + (size_t)blockIdx.x * 4096 + threadIdx.x;
#pragma unroll
        for (int i = 0; i < 16; ++i) oz[i * 256] = z;
    }

    int b     = blockIdx.x >> 6;
    int chunk = blockIdx.x & (CHUNKS_Q - 1);
    int quad  = threadIdx.x & 15;
    int rowg  = threadIdx.x >> 4;

    const f4* qb = (const f4*)(q + (size_t)b * LL * DD);
    const f4* base = qb + (size_t)(chunk * ROWS_Q + rowg) * 16 + quad;

    double a0 = 0.0, a1 = 0.0, a2 = 0.0, a3 = 0.0;
    f4 vb[8];
#pragma unroll
    for (int batch = 0; batch < 4; ++batch) {
#pragma unroll
        for (int j = 0; j < 8; ++j)
            vb[j] = base[(size_t)(batch * 8 + j) * 256];
#pragma unroll
        for (int j = 0; j < 8; ++j) {
            a0 += (double)fmaxf(vb[j].x, 0.0f) + 1e-3;
            a1 += (double)fmaxf(vb[j].y, 0.0f) + 1e-3;
            a2 += (double)fmaxf(vb[j].z, 0.0f) + 1e-3;
            a3 += (double)fmaxf(vb[j].w, 0.0f) + 1e-3;
        }
    }

    __shared__ double lds[16][16][5];
    lds[rowg][quad][0] = a0; lds[rowg][quad][1] = a1;
    lds[rowg][quad][2] = a2; lds[rowg][quad][3] = a3;
    __syncthreads();
    for (int s = 8; s > 0; s >>= 1) {
        if (rowg < s) {
            lds[rowg][quad][0] += lds[rowg + s][quad][0];
            lds[rowg][quad][1] += lds[rowg + s][quad][1];
            lds[rowg][quad][2] += lds[rowg + s][quad][2];
            lds[rowg][quad][3] += lds[rowg + s][quad][3];
        }
        __syncthreads();
    }
    if (rowg == 0) {
        double* pp = part + ((size_t)b * CHUNKS_Q + chunk) * DD;
        pp[quad * 4 + 0] = lds[0][quad][0];
        pp[quad * 4 + 1] = lds[0][quad][1];
        pp[quad * 4 + 2] = lds[0][quad][2];
        pp[quad * 4 + 3] = lds[0][quad][3];
    }
}

// ---------------- Kernel 2: scores + AND/OR + global 4096-bin digit histogram ----------------
__global__ __launch_bounds__(256) void k_scores(const float* __restrict__ k,
                                                const double* __restrict__ part,
                                                double* __restrict__ scores,
                                                float* __restrict__ out,
                                                unsigned long long* __restrict__ gAnd,
                                                unsigned long long* __restrict__ gOr,
                                                unsigned int* __restrict__ ghist) {
    __shared__ double s_part[4][DD];
    __shared__ double s_rq[DD];
    __shared__ unsigned long long sA2[4], sO2[4];

    {
        f4 z = (f4)(0.0f);
        f4* oz = (f4*)out + (size_t)(OUT_F4 / 2)
               + (size_t)blockIdx.x * 2048 + threadIdx.x;
#pragma unroll
        for (int i = 0; i < 8; ++i) oz[i * 256] = z;
    }

    const int RPB = 256;
    int b     = blockIdx.x >> 7;
    int chunk = blockIdx.x & 127;

    {
        int d = threadIdx.x & 63;
        int g = threadIdx.x >> 6;
        const double* pp = part + (size_t)b * CHUNKS_Q * DD;
        double acc = 0.0;
#pragma unroll
        for (int j = 0; j < 16; ++j)
            acc += pp[(size_t)(g * 16 + j) * DD + d];
        s_part[g][d] = acc;
    }
    __syncthreads();
    if (threadIdx.x < DD) {
        int d = threadIdx.x;
        s_rq[d] = (s_part[0][d] + s_part[1][d]) + (s_part[2][d] + s_part[3][d]);
    }
    __syncthreads();

    int sub   = threadIdx.x & 15;
    int rowIn = threadIdx.x >> 4;

    double r0 = s_rq[sub * 4 + 0];
    double r1 = s_rq[sub * 4 + 1];
    double r2 = s_rq[sub * 4 + 2];
    double r3 = s_rq[sub * 4 + 3];

    const f4* kb = (const f4*)(k + (size_t)b * LL * DD);
    int l0 = chunk * RPB;
    const f4* base = kb + (size_t)(l0 + rowIn) * 16 + sub;

    unsigned long long ma = ~0ULL, mo = 0ULL;
    f4 vb[8];
    double sv[8];
#pragma unroll
    for (int batch = 0; batch < 2; ++batch) {
#pragma unroll
        for (int i = 0; i < 8; ++i)
            vb[i] = base[(size_t)(batch * 8 + i) * 256];
#pragma unroll
        for (int i = 0; i < 8; ++i) {
            sv[i] = r0 * ((double)fmaxf(vb[i].x, 0.0f) + 1e-3)
                  + r1 * ((double)fmaxf(vb[i].y, 0.0f) + 1e-3)
                  + r2 * ((double)fmaxf(vb[i].z, 0.0f) + 1e-3)
                  + r3 * ((double)fmaxf(vb[i].w, 0.0f) + 1e-3);
        }
#pragma unroll
        for (int i = 0; i < 8; ++i) {
            double s = sv[i];
            s += __shfl_xor(s, 1, 16);
            s += __shfl_xor(s, 2, 16);
            s += __shfl_xor(s, 4, 16);
            s += __shfl_xor(s, 8, 16);
            if (sub == 0) {
                scores[(size_t)b * LL + l0 + rowIn + 16 * (batch * 8 + i)] = s;
                unsigned long long u = (unsigned long long)__double_as_longlong(s);
                ma &= u; mo |= u;
                atomicAdd(&ghist[b * 4096 + (unsigned int)((u >> 44) & 4095ULL)], 1u);
            }
        }
    }

#pragma unroll
    for (int off = 32; off >= 1; off >>= 1) {
        ma &= __shfl_xor(ma, off);
        mo |= __shfl_xor(mo, off);
    }
    if ((threadIdx.x & 63) == 0) { sA2[threadIdx.x >> 6] = ma; sO2[threadIdx.x >> 6] = mo; }
    __syncthreads();
    if (threadIdx.x == 0) {
        atomicAnd(&gAnd[b], sA2[0] & sA2[1] & sA2[2] & sA2[3]);
        atomicOr(&gOr[b], sO2[0] | sO2[1] | sO2[2] | sO2[3]);
    }
}

// ---- shared: suffix-scan the 4096-bin histogram, find cutoff bin + within-bin rank ----
__device__ __forceinline__ void find_cut(const unsigned int* __restrict__ hb, int r, int tid,
                                         unsigned int* sfx, unsigned int* sW,
                                         int* s_cb, int* s_rp) {
    unsigned int h[16], sl[16];
#pragma unroll
    for (int j = 0; j < 16; ++j) h[j] = hb[tid * 16 + j];
    unsigned int run = 0;
#pragma unroll
    for (int j = 15; j >= 0; --j) { run += h[j]; sl[j] = run; }
    unsigned int tot = run, vv = tot;
    int lane = tid & 63;
#pragma unroll
    for (int off = 1; off < 64; off <<= 1) {
        unsigned int t = __shfl_down(vv, off);
        if (lane + off < 64) vv += t;
    }
    if (lane == 0) sW[tid >> 6] = vv;
    __syncthreads();
    unsigned int add = 0;
    int w = tid >> 6;
#pragma unroll
    for (int ww = 0; ww < 4; ++ww) if (ww > w) add += sW[ww];
    unsigned int above = (vv + add) - tot;
#pragma unroll
    for (int j = 0; j < 16; ++j) sfx[tid * 16 + j] = above + sl[j];
    __syncthreads();
#pragma unroll
    for (int j = 0; j < 16; ++j) {
        int d = tid * 16 + j;
        unsigned int S  = sfx[d];
        unsigned int Sn = (d == 4095) ? 0u : sfx[d + 1];
        if (S > (unsigned int)r && Sn <= (unsigned int)r) { *s_cb = d; *s_rp = r - (int)Sn; }
    }
    __syncthreads();
}

// ---------------- Kernel 3: parallel gather (1024 blocks; 256 keys each) ----------------
__global__ __launch_bounds__(256) void k_gather(const double* __restrict__ scores,
                                                const unsigned long long* __restrict__ gAnd,
                                                const unsigned long long* __restrict__ gOr,
                                                const unsigned int* __restrict__ ghist,
                                                const int* __restrict__ topk_p,
                                                unsigned int* __restrict__ eqCnt,
                                                unsigned long long* __restrict__ eqKey,
                                                unsigned int* __restrict__ eqIdx,
                                                const float* __restrict__ v,
                                                float* __restrict__ out) {
    int b   = blockIdx.x >> 7;
    int blk = blockIdx.x & 127;
    int tid = threadIdx.x;
    unsigned long long A = gAnd[b], O = gOr[b];
    if (A == O) return;                         // all scores equal: nothing selected
    if (((A ^ O) >> 56) != 0ULL) return;        // top byte varies: k_final fallback handles

    __shared__ unsigned int sfx[4096];
    __shared__ unsigned int sW[4];
    __shared__ int s_cb, s_rp, s_cnt;
    __shared__ int s_idx[MAXSEL];
    if (tid == 0) s_cnt = 0;
    find_cut(ghist + b * 4096, topk_p[0], tid, sfx, sW, &s_cb, &s_rp);
    int cb = s_cb;

    int l = blk * 256 + tid;
    unsigned long long key =
        ((const unsigned long long*)(scores + (size_t)b * LL))[l];
    int digit = (int)((key >> 44) & 4095ULL);
    if (digit > cb) {
        int sl = atomicAdd(&s_cnt, 1);
        if (sl < MAXSEL) s_idx[sl] = l;
    } else if (digit == cb) {
        unsigned int slot = atomicAdd(&eqCnt[b], 1u);
        if (slot < ECAP) {
            eqKey[(size_t)b * ECAP + slot] = key;
            eqIdx[(size_t)b * ECAP + slot] = (unsigned int)l;
        }
    }
    __syncthreads();
    int cnt = s_cnt < MAXSEL ? s_cnt : MAXSEL;
    int g = tid >> 4, lane16 = tid & 15;
    for (int r2 = g; r2 < cnt; r2 += 16) {
        size_t rowOff = ((size_t)b * LL + s_idx[r2]) * DD;
        ((f4*)(out + rowOff))[lane16] = ((const f4*)(v + rowOff))[lane16];
    }
}

// ---------------- Kernel 4: exact kappa among eq-bin keys + their gather ----------------
__global__ __launch_bounds__(256) void k_final(const double* __restrict__ scores,
                                               const unsigned long long* __restrict__ gAnd,
                                               const unsigned long long* __restrict__ gOr,
                                               const unsigned int* __restrict__ ghist,
                                               const int* __restrict__ topk_p,
                                               const unsigned int* __restrict__ eqCnt,
                                               const unsigned long long* __restrict__ eqKey,
                                               const unsigned int* __restrict__ eqIdx,
                                               const float* __restrict__ v,
                                               float* __restrict__ out) {
    int b = blockIdx.x, tid = threadIdx.x;
    unsigned long long A = gAnd[b], O = gOr[b];
    if (A == O) return;

    __shared__ unsigned int sfx[4096];
    __shared__ unsigned int sW[4];
    __shared__ int s_cb, s_rp, s_cnt;
    __shared__ int s_idx[MAXSEL];
    __shared__ unsigned long long eqL[ECAP];
    __shared__ unsigned long long sKappa;

    bool fbByte = ((A ^ O) >> 56) != 0ULL;
    unsigned int nc = eqCnt[b];

    if (!fbByte && nc <= ECAP) {
        find_cut(ghist + b * 4096, topk_p[0], tid, sfx, sW, &s_cb, &s_rp);
        int rp = s_rp;

        for (unsigned int i = tid; i < nc; i += 256)
            eqL[i] = eqKey[(size_t)b * ECAP + i];
        __syncthreads();

        // kappa = rp-th largest (0-based) among eq keys (duplicates handled)
        for (unsigned int i = tid; i < nc; i += 256) {
            unsigned long long ki = eqL[i];
            int cg = 0, ce = 0;
            for (unsigned int j = 0; j < nc; ++j) {
                unsigned long long kj = eqL[j];
                cg += (kj > ki);
                ce += (kj == ki);
            }
            if (cg <= rp && rp < cg + ce) sKappa = ki;
        }
        __syncthreads();
        unsigned long long kap = sKappa;
        if (tid == 0) s_cnt = 0;
        __syncthreads();
        for (unsigned int i = tid; i < nc; i += 256) {
            if (eqL[i] > kap) {
                int sl = atomicAdd(&s_cnt, 1);
                if (sl < MAXSEL) s_idx[sl] = (int)eqIdx[(size_t)b * ECAP + i];
            }
        }
        __syncthreads();
    } else {
        // slow correctness fallback (never hit for this data): 8-pass streaming radix
        __shared__ unsigned int h2[256];
        __shared__ unsigned long long pfx;
        __shared__ int rr;
        if (tid == 0) { pfx = 0ULL; rr = topk_p[0]; }
        __syncthreads();
        const unsigned long long* sb =
            (const unsigned long long*)(scores + (size_t)b * LL);
        for (int shift = 56; shift >= 0; shift -= 8) {
            h2[tid] = 0;
            __syncthreads();
            unsigned long long hm = (shift == 56) ? 0ULL : (~0ULL << (shift + 8));
            unsigned long long p = pfx;
            for (int l = tid; l < LL; l += 256) {
                unsigned long long kk = sb[l];
                if ((kk & hm) == p)
                    atomicAdd(&h2[(unsigned int)(kk >> shift) & 255u], 1u);
            }
            __syncthreads();
            if (tid == 0) {
                int r = rr; unsigned int cum = 0; int dg = 0;
                for (int i = 255; i >= 0; --i) {
                    unsigned int hh = h2[i];
                    if (cum + hh > (unsigned int)r) { dg = i; rr = r - (int)cum; break; }
                    cum += hh;
                }
                pfx |= ((unsigned long long)dg << shift);
            }
            __syncthreads();
        }
        unsigned long long kap = pfx;
        if (tid == 0) s_cnt = 0;
        __syncthreads();
        for (int l = tid; l < LL; l += 256) {
            if (sb[l] > kap) {
                int sl = atomicAdd(&s_cnt, 1);
                if (sl < MAXSEL) s_idx[sl] = l;
            }
        }
        __syncthreads();
    }

    int cnt = s_cnt < MAXSEL ? s_cnt : MAXSEL;
    int g = tid >> 4, lane16 = tid & 15;
    for (int r2 = g; r2 < cnt; r2 += 16) {
        size_t rowOff = ((size_t)b * LL + s_idx[r2]) * DD;
        ((f4*)(out + rowOff))[lane16] = ((const f4*)(v + rowOff))[lane16];
    }
}

extern "C" void kernel_launch(void* const* d_in, const int* in_sizes, int n_in,
                              void* d_out, int out_size, void* d_ws, size_t ws_size,
                              hipStream_t stream) {
    const float* q = (const float*)d_in[0];
    const float* k = (const float*)d_in[1];
    const float* v = (const float*)d_in[2];
    const int* topk = (const int*)d_in[3];
    float* out = (float*)d_out;

    double* part   = (double*)d_ws;
    double* scores = (double*)((char*)d_ws + 0x40000);
    unsigned int*       ghist = (unsigned int*)((char*)d_ws + 0x240000);
    unsigned long long* gAnd  = (unsigned long long*)((char*)d_ws + 0x260000);
    unsigned long long* gOr   = (unsigned long long*)((char*)d_ws + 0x260040);
    unsigned int*       eqCnt = (unsigned int*)((char*)d_ws + 0x260080);
    unsigned long long* eqKey = (unsigned long long*)((char*)d_ws + 0x260100);
    unsigned int*       eqIdx = (unsigned int*)((char*)d_ws + 0x260100 + (size_t)BB * ECAP * 8);

    k_reduce_q<<<BB * CHUNKS_Q, 256, 0, stream>>>(q, part, out, ghist, gAnd, gOr, eqCnt);
    k_scores<<<BB * (LL / 256), 256, 0, stream>>>(k, part, scores, out, gAnd, gOr, ghist);
    k_gather<<<BB * 128, 256, 0, stream>>>(scores, gAnd, gOr, ghist, topk, eqCnt, eqKey, eqIdx, v, out);
    k_final<<<BB, 256, 0, stream>>>(scores, gAnd, gOr, ghist, topk, eqCnt, eqKey, eqIdx, v, out);
}

// Round 15
// 121.581 us; speedup vs baseline: 3.8419x; 3.8419x over previous
//
#include <hip/hip_runtime.h>

#define BB 8
#define LL 32768
#define DD 64

typedef float f4 __attribute__((ext_vector_type(4)));

// ws layout:
// [0, 0x40000)       : double part[BB][CHUNKS_Q][DD]
// [0x40000, 0x240000): double scores[BB*LL]
// [0x240000]         : u32 ghist[BB][4096] (zeroed by k1 blocks 0..127)
// [0x260000]         : u64 gAnd[8]; [0x260040] u64 gOr[8]; [0x260080] u32 eqCnt[8]
// [0x260100]         : u64 eqKey[BB][ECAP]; then u32 eqIdx[BB][ECAP]

#define OUT_F4 (BB * LL * DD / 4)
#define CHUNKS_Q 64
#define ROWS_Q (LL / CHUNKS_Q)
#define ECAP 2048
#define MAXSEL 96

// window shift from completed AND/OR: top 12 varying bits (always monotone for positive doubles)
__device__ __forceinline__ int win_shift(unsigned long long A, unsigned long long O) {
    unsigned long long x = A ^ O;           // nonzero when called
    int p = 63 - __clzll(x);                // highest varying bit
    return (p >= 11) ? (p - 11) : 0;
}

// ---------------- Kernel 1: per-chunk partials + zero-fill + ws init ----------------
__global__ __launch_bounds__(256) void k_reduce_q(const float* __restrict__ q,
                                                  double* __restrict__ part,
                                                  float* __restrict__ out,
                                                  unsigned int* __restrict__ ghist,
                                                  unsigned long long* __restrict__ gAnd,
                                                  unsigned long long* __restrict__ gOr,
                                                  unsigned int* __restrict__ eqCnt) {
    if (blockIdx.x < 128) ghist[blockIdx.x * 256 + threadIdx.x] = 0;
    if (blockIdx.x == 128 && threadIdx.x < BB) {
        gAnd[threadIdx.x] = ~0ULL; gOr[threadIdx.x] = 0ULL; eqCnt[threadIdx.x] = 0u;
    }
    {
        f4 z = (f4)(0.0f);
        f4* oz = (f4*)out + (size_t)blockIdx.x * 4096 + threadIdx.x;
#pragma unroll
        for (int i = 0; i < 16; ++i) oz[i * 256] = z;
    }

    int b     = blockIdx.x >> 6;
    int chunk = blockIdx.x & (CHUNKS_Q - 1);
    int quad  = threadIdx.x & 15;
    int rowg  = threadIdx.x >> 4;

    const f4* qb = (const f4*)(q + (size_t)b * LL * DD);
    const f4* base = qb + (size_t)(chunk * ROWS_Q + rowg) * 16 + quad;

    double a0 = 0.0, a1 = 0.0, a2 = 0.0, a3 = 0.0;
    f4 vb[8];
#pragma unroll
    for (int batch = 0; batch < 4; ++batch) {
#pragma unroll
        for (int j = 0; j < 8; ++j)
            vb[j] = base[(size_t)(batch * 8 + j) * 256];
#pragma unroll
        for (int j = 0; j < 8; ++j) {
            a0 += (double)fmaxf(vb[j].x, 0.0f) + 1e-3;
            a1 += (double)fmaxf(vb[j].y, 0.0f) + 1e-3;
            a2 += (double)fmaxf(vb[j].z, 0.0f) + 1e-3;
            a3 += (double)fmaxf(vb[j].w, 0.0f) + 1e-3;
        }
    }

    __shared__ double lds[16][16][5];
    lds[rowg][quad][0] = a0; lds[rowg][quad][1] = a1;
    lds[rowg][quad][2] = a2; lds[rowg][quad][3] = a3;
    __syncthreads();
    for (int s = 8; s > 0; s >>= 1) {
        if (rowg < s) {
            lds[rowg][quad][0] += lds[rowg + s][quad][0];
            lds[rowg][quad][1] += lds[rowg + s][quad][1];
            lds[rowg][quad][2] += lds[rowg + s][quad][2];
            lds[rowg][quad][3] += lds[rowg + s][quad][3];
        }
        __syncthreads();
    }
    if (rowg == 0) {
        double* pp = part + ((size_t)b * CHUNKS_Q + chunk) * DD;
        pp[quad * 4 + 0] = lds[0][quad][0];
        pp[quad * 4 + 1] = lds[0][quad][1];
        pp[quad * 4 + 2] = lds[0][quad][2];
        pp[quad * 4 + 3] = lds[0][quad][3];
    }
}

// ---------------- Kernel 2: scores + AND/OR ----------------
__global__ __launch_bounds__(256) void k_scores(const float* __restrict__ k,
                                                const double* __restrict__ part,
                                                double* __restrict__ scores,
                                                float* __restrict__ out,
                                                unsigned long long* __restrict__ gAnd,
                                                unsigned long long* __restrict__ gOr) {
    __shared__ double s_part[4][DD];
    __shared__ double s_rq[DD];
    __shared__ unsigned long long sA2[4], sO2[4];

    {
        f4 z = (f4)(0.0f);
        f4* oz = (f4*)out + (size_t)(OUT_F4 / 2)
               + (size_t)blockIdx.x * 2048 + threadIdx.x;
#pragma unroll
        for (int i = 0; i < 8; ++i) oz[i * 256] = z;
    }

    const int RPB = 256;
    int b     = blockIdx.x >> 7;
    int chunk = blockIdx.x & 127;

    {
        int d = threadIdx.x & 63;
        int g = threadIdx.x >> 6;
        const double* pp = part + (size_t)b * CHUNKS_Q * DD;
        double acc = 0.0;
#pragma unroll
        for (int j = 0; j < 16; ++j)
            acc += pp[(size_t)(g * 16 + j) * DD + d];
        s_part[g][d] = acc;
    }
    __syncthreads();
    if (threadIdx.x < DD) {
        int d = threadIdx.x;
        s_rq[d] = (s_part[0][d] + s_part[1][d]) + (s_part[2][d] + s_part[3][d]);
    }
    __syncthreads();

    int sub   = threadIdx.x & 15;
    int rowIn = threadIdx.x >> 4;

    double r0 = s_rq[sub * 4 + 0];
    double r1 = s_rq[sub * 4 + 1];
    double r2 = s_rq[sub * 4 + 2];
    double r3 = s_rq[sub * 4 + 3];

    const f4* kb = (const f4*)(k + (size_t)b * LL * DD);
    int l0 = chunk * RPB;
    const f4* base = kb + (size_t)(l0 + rowIn) * 16 + sub;

    unsigned long long ma = ~0ULL, mo = 0ULL;
    f4 vb[8];
    double sv[8];
#pragma unroll
    for (int batch = 0; batch < 2; ++batch) {
#pragma unroll
        for (int i = 0; i < 8; ++i)
            vb[i] = base[(size_t)(batch * 8 + i) * 256];
#pragma unroll
        for (int i = 0; i < 8; ++i) {
            sv[i] = r0 * ((double)fmaxf(vb[i].x, 0.0f) + 1e-3)
                  + r1 * ((double)fmaxf(vb[i].y, 0.0f) + 1e-3)
                  + r2 * ((double)fmaxf(vb[i].z, 0.0f) + 1e-3)
                  + r3 * ((double)fmaxf(vb[i].w, 0.0f) + 1e-3);
        }
#pragma unroll
        for (int i = 0; i < 8; ++i) {
            double s = sv[i];
            s += __shfl_xor(s, 1, 16);
            s += __shfl_xor(s, 2, 16);
            s += __shfl_xor(s, 4, 16);
            s += __shfl_xor(s, 8, 16);
            if (sub == 0) {
                scores[(size_t)b * LL + l0 + rowIn + 16 * (batch * 8 + i)] = s;
                unsigned long long u = (unsigned long long)__double_as_longlong(s);
                ma &= u; mo |= u;
            }
        }
    }

#pragma unroll
    for (int off = 32; off >= 1; off >>= 1) {
        ma &= __shfl_xor(ma, off);
        mo |= __shfl_xor(mo, off);
    }
    if ((threadIdx.x & 63) == 0) { sA2[threadIdx.x >> 6] = ma; sO2[threadIdx.x >> 6] = mo; }
    __syncthreads();
    if (threadIdx.x == 0) {
        atomicAnd(&gAnd[b], sA2[0] & sA2[1] & sA2[2] & sA2[3]);
        atomicOr(&gOr[b], sO2[0] | sO2[1] | sO2[2] | sO2[3]);
    }
}

// ---------------- Kernel 3: global 4096-bin histogram at the adaptive window ----------------
__global__ __launch_bounds__(256) void k_hist(const double* __restrict__ scores,
                                              const unsigned long long* __restrict__ gAnd,
                                              const unsigned long long* __restrict__ gOr,
                                              unsigned int* __restrict__ ghist) {
    int b   = blockIdx.x >> 7;
    int blk = blockIdx.x & 127;
    unsigned long long A = gAnd[b], O = gOr[b];
    if (A == O) return;
    int s = win_shift(A, O);
    int l = blk * 256 + threadIdx.x;
    unsigned long long key =
        ((const unsigned long long*)(scores + (size_t)b * LL))[l];
    atomicAdd(&ghist[b * 4096 + (unsigned int)((key >> s) & 4095ULL)], 1u);
}

// ---- shared: suffix-scan the 4096-bin histogram -> cutoff bin cb + within-bin rank rp ----
__device__ __forceinline__ void find_cut(const unsigned int* __restrict__ hb, int r, int tid,
                                         unsigned int* sfx, unsigned int* sW,
                                         int* s_cb, int* s_rp) {
    unsigned int h[16], sl[16];
#pragma unroll
    for (int j = 0; j < 16; ++j) h[j] = hb[tid * 16 + j];
    unsigned int run = 0;
#pragma unroll
    for (int j = 15; j >= 0; --j) { run += h[j]; sl[j] = run; }
    unsigned int tot = run, vv = tot;
    int lane = tid & 63;
#pragma unroll
    for (int off = 1; off < 64; off <<= 1) {
        unsigned int t = __shfl_down(vv, off);
        if (lane + off < 64) vv += t;
    }
    if (lane == 0) sW[tid >> 6] = vv;
    __syncthreads();
    unsigned int add = 0;
    int w = tid >> 6;
#pragma unroll
    for (int ww = 0; ww < 4; ++ww) if (ww > w) add += sW[ww];
    unsigned int above = (vv + add) - tot;
#pragma unroll
    for (int j = 0; j < 16; ++j) sfx[tid * 16 + j] = above + sl[j];
    __syncthreads();
#pragma unroll
    for (int j = 0; j < 16; ++j) {
        int d = tid * 16 + j;
        unsigned int S  = sfx[d];
        unsigned int Sn = (d == 4095) ? 0u : sfx[d + 1];
        if (S > (unsigned int)r && Sn <= (unsigned int)r) { *s_cb = d; *s_rp = r - (int)Sn; }
    }
    __syncthreads();
}

// ---------------- Kernel 4: parallel classify+gather (1024 blocks; 256 keys each) ----------------
__global__ __launch_bounds__(256) void k_gather(const double* __restrict__ scores,
                                                const unsigned long long* __restrict__ gAnd,
                                                const unsigned long long* __restrict__ gOr,
                                                const unsigned int* __restrict__ ghist,
                                                const int* __restrict__ topk_p,
                                                unsigned int* __restrict__ eqCnt,
                                                unsigned long long* __restrict__ eqKey,
                                                unsigned int* __restrict__ eqIdx,
                                                const float* __restrict__ v,
                                                float* __restrict__ out) {
    int b   = blockIdx.x >> 7;
    int blk = blockIdx.x & 127;
    int tid = threadIdx.x;
    unsigned long long A = gAnd[b], O = gOr[b];
    if (A == O) return;                 // all scores equal -> nothing selected
    int s = win_shift(A, O);

    __shared__ unsigned int sfx[4096];
    __shared__ unsigned int sW[4];
    __shared__ int s_cb, s_rp, s_cnt;
    __shared__ int s_idx[MAXSEL];
    if (tid == 0) s_cnt = 0;
    find_cut(ghist + b * 4096, topk_p[0], tid, sfx, sW, &s_cb, &s_rp);
    int cb = s_cb;

    int l = blk * 256 + tid;
    unsigned long long key =
        ((const unsigned long long*)(scores + (size_t)b * LL))[l];
    int digit = (int)((key >> s) & 4095ULL);
    if (digit > cb) {
        int sl = atomicAdd(&s_cnt, 1);
        if (sl < MAXSEL) s_idx[sl] = l;
    } else if (digit == cb) {
        unsigned int slot = atomicAdd(&eqCnt[b], 1u);
        if (slot < ECAP) {
            eqKey[(size_t)b * ECAP + slot] = key;
            eqIdx[(size_t)b * ECAP + slot] = (unsigned int)l;
        }
    }
    __syncthreads();
    int cnt = s_cnt < MAXSEL ? s_cnt : MAXSEL;
    int g = tid >> 4, lane16 = tid & 15;
    for (int r2 = g; r2 < cnt; r2 += 16) {
        size_t rowOff = ((size_t)b * LL + s_idx[r2]) * DD;
        ((f4*)(out + rowOff))[lane16] = ((const f4*)(v + rowOff))[lane16];
    }
}

// ---------------- Kernel 5: exact kappa among eq-bin keys + their gather ----------------
__global__ __launch_bounds__(256) void k_final(const double* __restrict__ scores,
                                               const unsigned long long* __restrict__ gAnd,
                                               const unsigned long long* __restrict__ gOr,
                                               const unsigned int* __restrict__ ghist,
                                               const int* __restrict__ topk_p,
                                               const unsigned int* __restrict__ eqCnt,
                                               const unsigned long long* __restrict__ eqKey,
                                               const unsigned int* __restrict__ eqIdx,
                                               const float* __restrict__ v,
                                               float* __restrict__ out) {
    int b = blockIdx.x, tid = threadIdx.x;
    unsigned long long A = gAnd[b], O = gOr[b];
    if (A == O) return;

    __shared__ unsigned int sfx[4096];
    __shared__ unsigned int sW[4];
    __shared__ int s_cb, s_rp, s_cnt;
    __shared__ int s_idx[MAXSEL];
    __shared__ unsigned long long eqL[ECAP];
    __shared__ unsigned long long sKappa;

    unsigned int nc = eqCnt[b];

    if (nc <= ECAP) {
        find_cut(ghist + b * 4096, topk_p[0], tid, sfx, sW, &s_cb, &s_rp);
        int rp = s_rp;

        for (unsigned int i = tid; i < nc; i += 256)
            eqL[i] = eqKey[(size_t)b * ECAP + i];
        __syncthreads();

        // kappa = rp-th largest (0-based) among eq keys (duplicates handled)
        for (unsigned int i = tid; i < nc; i += 256) {
            unsigned long long ki = eqL[i];
            int cg = 0, ce = 0;
            for (unsigned int j = 0; j < nc; ++j) {
                unsigned long long kj = eqL[j];
                cg += (kj > ki);
                ce += (kj == ki);
            }
            if (cg <= rp && rp < cg + ce) sKappa = ki;
        }
        __syncthreads();
        unsigned long long kap = sKappa;
        if (tid == 0) s_cnt = 0;
        __syncthreads();
        for (unsigned int i = tid; i < nc; i += 256) {
            if (eqL[i] > kap) {
                int sl = atomicAdd(&s_cnt, 1);
                if (sl < MAXSEL) s_idx[sl] = (int)eqIdx[(size_t)b * ECAP + i];
            }
        }
        __syncthreads();
    } else {
        // correctness net (eq overflow — not expected): streaming 8-pass radix
        __shared__ unsigned int h2[256];
        __shared__ unsigned long long pfx;
        __shared__ int rr;
        if (tid == 0) { pfx = 0ULL; rr = topk_p[0]; }
        __syncthreads();
        const unsigned long long* sb =
            (const unsigned long long*)(scores + (size_t)b * LL);
        for (int shift = 56; shift >= 0; shift -= 8) {
            h2[tid] = 0;
            __syncthreads();
            unsigned long long hm = (shift == 56) ? 0ULL : (~0ULL << (shift + 8));
            unsigned long long p = pfx;
            for (int l = tid; l < LL; l += 256) {
                unsigned long long kk = sb[l];
                if ((kk & hm) == p)
                    atomicAdd(&h2[(unsigned int)(kk >> shift) & 255u], 1u);
            }
            __syncthreads();
            if (tid == 0) {
                int r = rr; unsigned int cum = 0; int dg = 0;
                for (int i = 255; i >= 0; --i) {
                    unsigned int hh = h2[i];
                    if (cum + hh > (unsigned int)r) { dg = i; rr = r - (int)cum; break; }
                    cum += hh;
                }
                pfx |= ((unsigned long long)dg << shift);
            }
            __syncthreads();
        }
        unsigned long long kap = pfx;
        if (tid == 0) s_cnt = 0;
        __syncthreads();
        for (int l = tid; l < LL; l += 256) {
            if (sb[l] > kap) {
                int sl = atomicAdd(&s_cnt, 1);
                if (sl < MAXSEL) s_idx[sl] = l;
            }
        }
        __syncthreads();
    }

    int cnt = s_cnt < MAXSEL ? s_cnt : MAXSEL;
    int g = tid >> 4, lane16 = tid & 15;
    for (int r2 = g; r2 < cnt; r2 += 16) {
        size_t rowOff = ((size_t)b * LL + s_idx[r2]) * DD;
        ((f4*)(out + rowOff))[lane16] = ((const f4*)(v + rowOff))[lane16];
    }
}

extern "C" void kernel_launch(void* const* d_in, const int* in_sizes, int n_in,
                              void* d_out, int out_size, void* d_ws, size_t ws_size,
                              hipStream_t stream) {
    const float* q = (const float*)d_in[0];
    const float* k = (const float*)d_in[1];
    const float* v = (const float*)d_in[2];
    const int* topk = (const int*)d_in[3];
    float* out = (float*)d_out;

    double* part   = (double*)d_ws;
    double* scores = (double*)((char*)d_ws + 0x40000);
    unsigned int*       ghist = (unsigned int*)((char*)d_ws + 0x240000);
    unsigned long long* gAnd  = (unsigned long long*)((char*)d_ws + 0x260000);
    unsigned long long* gOr   = (unsigned long long*)((char*)d_ws + 0x260040);
    unsigned int*       eqCnt = (unsigned int*)((char*)d_ws + 0x260080);
    unsigned long long* eqKey = (unsigned long long*)((char*)d_ws + 0x260100);
    unsigned int*       eqIdx = (unsigned int*)((char*)d_ws + 0x260100 + (size_t)BB * ECAP * 8);

    k_reduce_q<<<BB * CHUNKS_Q, 256, 0, stream>>>(q, part, out, ghist, gAnd, gOr, eqCnt);
    k_scores<<<BB * (LL / 256), 256, 0, stream>>>(k, part, scores, out, gAnd, gOr);
    k_hist<<<BB * 128, 256, 0, stream>>>(scores, gAnd, gOr, ghist);
    k_gather<<<BB * 128, 256, 0, stream>>>(scores, gAnd, gOr, ghist, topk, eqCnt, eqKey, eqIdx, v, out);
    k_final<<<BB, 256, 0, stream>>>(scores, gAnd, gOr, ghist, topk, eqCnt, eqKey, eqIdx, v, out);
}

// Round 16
// 63.067 us; speedup vs baseline: 7.4065x; 1.9278x over previous
//
#include <hip/hip_runtime.h>

#define BB 8
#define LL 32768
#define DD 64

typedef float f4 __attribute__((ext_vector_type(4)));
typedef unsigned long long u64x2 __attribute__((ext_vector_type(2)));

// ws layout:
// [0, 0x40000)       : double part[BB][CHUNKS_Q][DD]
// [0x40000, 0x240000): double scores[BB*LL]
// [0x240000]         : u32 ghist[BB][4096] (zeroed by k1 blocks 0..127)
// [0x260000]         : u64 gAnd[8]; [0x260040] u64 gOr[8]; [0x260080] u32 eqCnt[8]
// [0x260100]         : u64 eqKey[BB][ECAP]; then u32 eqIdx[BB][ECAP]

#define OUT_F4 (BB * LL * DD / 4)
#define CHUNKS_Q 64
#define ROWS_Q (LL / CHUNKS_Q)
#define ECAP 2048
#define MAXSEL 96

// window shift from completed AND/OR: top 12 varying bits (monotone for positive doubles)
__device__ __forceinline__ int win_shift(unsigned long long A, unsigned long long O) {
    unsigned long long x = A ^ O;           // nonzero when called
    int p = 63 - __clzll(x);                // highest varying bit
    return (p >= 11) ? (p - 11) : 0;
}

// ---------------- Kernel 1: per-chunk partials + zero-fill + ws init ----------------
__global__ __launch_bounds__(256) void k_reduce_q(const float* __restrict__ q,
                                                  double* __restrict__ part,
                                                  float* __restrict__ out,
                                                  unsigned int* __restrict__ ghist,
                                                  unsigned long long* __restrict__ gAnd,
                                                  unsigned long long* __restrict__ gOr,
                                                  unsigned int* __restrict__ eqCnt) {
    if (blockIdx.x < 128) ghist[blockIdx.x * 256 + threadIdx.x] = 0;
    if (blockIdx.x == 128 && threadIdx.x < BB) {
        gAnd[threadIdx.x] = ~0ULL; gOr[threadIdx.x] = 0ULL; eqCnt[threadIdx.x] = 0u;
    }
    {
        f4 z = (f4)(0.0f);
        f4* oz = (f4*)out + (size_t)blockIdx.x * 4096 + threadIdx.x;
#pragma unroll
        for (int i = 0; i < 16; ++i) oz[i * 256] = z;
    }

    int b     = blockIdx.x >> 6;
    int chunk = blockIdx.x & (CHUNKS_Q - 1);
    int quad  = threadIdx.x & 15;
    int rowg  = threadIdx.x >> 4;

    const f4* qb = (const f4*)(q + (size_t)b * LL * DD);
    const f4* base = qb + (size_t)(chunk * ROWS_Q + rowg) * 16 + quad;

    double a0 = 0.0, a1 = 0.0, a2 = 0.0, a3 = 0.0;
    f4 vb[8];
#pragma unroll
    for (int batch = 0; batch < 4; ++batch) {
#pragma unroll
        for (int j = 0; j < 8; ++j)
            vb[j] = base[(size_t)(batch * 8 + j) * 256];
#pragma unroll
        for (int j = 0; j < 8; ++j) {
            a0 += (double)fmaxf(vb[j].x, 0.0f) + 1e-3;
            a1 += (double)fmaxf(vb[j].y, 0.0f) + 1e-3;
            a2 += (double)fmaxf(vb[j].z, 0.0f) + 1e-3;
            a3 += (double)fmaxf(vb[j].w, 0.0f) + 1e-3;
        }
    }

    __shared__ double lds[16][16][5];
    lds[rowg][quad][0] = a0; lds[rowg][quad][1] = a1;
    lds[rowg][quad][2] = a2; lds[rowg][quad][3] = a3;
    __syncthreads();
    for (int s = 8; s > 0; s >>= 1) {
        if (rowg < s) {
            lds[rowg][quad][0] += lds[rowg + s][quad][0];
            lds[rowg][quad][1] += lds[rowg + s][quad][1];
            lds[rowg][quad][2] += lds[rowg + s][quad][2];
            lds[rowg][quad][3] += lds[rowg + s][quad][3];
        }
        __syncthreads();
    }
    if (rowg == 0) {
        double* pp = part + ((size_t)b * CHUNKS_Q + chunk) * DD;
        pp[quad * 4 + 0] = lds[0][quad][0];
        pp[quad * 4 + 1] = lds[0][quad][1];
        pp[quad * 4 + 2] = lds[0][quad][2];
        pp[quad * 4 + 3] = lds[0][quad][3];
    }
}

// ---------------- Kernel 2: scores + AND/OR ----------------
__global__ __launch_bounds__(256) void k_scores(const float* __restrict__ k,
                                                const double* __restrict__ part,
                                                double* __restrict__ scores,
                                                float* __restrict__ out,
                                                unsigned long long* __restrict__ gAnd,
                                                unsigned long long* __restrict__ gOr) {
    __shared__ double s_part[4][DD];
    __shared__ double s_rq[DD];
    __shared__ unsigned long long sA2[4], sO2[4];

    {
        f4 z = (f4)(0.0f);
        f4* oz = (f4*)out + (size_t)(OUT_F4 / 2)
               + (size_t)blockIdx.x * 2048 + threadIdx.x;
#pragma unroll
        for (int i = 0; i < 8; ++i) oz[i * 256] = z;
    }

    const int RPB = 256;
    int b     = blockIdx.x >> 7;
    int chunk = blockIdx.x & 127;

    {
        int d = threadIdx.x & 63;
        int g = threadIdx.x >> 6;
        const double* pp = part + (size_t)b * CHUNKS_Q * DD;
        double acc = 0.0;
#pragma unroll
        for (int j = 0; j < 16; ++j)
            acc += pp[(size_t)(g * 16 + j) * DD + d];
        s_part[g][d] = acc;
    }
    __syncthreads();
    if (threadIdx.x < DD) {
        int d = threadIdx.x;
        s_rq[d] = (s_part[0][d] + s_part[1][d]) + (s_part[2][d] + s_part[3][d]);
    }
    __syncthreads();

    int sub   = threadIdx.x & 15;
    int rowIn = threadIdx.x >> 4;

    double r0 = s_rq[sub * 4 + 0];
    double r1 = s_rq[sub * 4 + 1];
    double r2 = s_rq[sub * 4 + 2];
    double r3 = s_rq[sub * 4 + 3];

    const f4* kb = (const f4*)(k + (size_t)b * LL * DD);
    int l0 = chunk * RPB;
    const f4* base = kb + (size_t)(l0 + rowIn) * 16 + sub;

    unsigned long long ma = ~0ULL, mo = 0ULL;
    f4 vb[8];
    double sv[8];
#pragma unroll
    for (int batch = 0; batch < 2; ++batch) {
#pragma unroll
        for (int i = 0; i < 8; ++i)
            vb[i] = base[(size_t)(batch * 8 + i) * 256];
#pragma unroll
        for (int i = 0; i < 8; ++i) {
            sv[i] = r0 * ((double)fmaxf(vb[i].x, 0.0f) + 1e-3)
                  + r1 * ((double)fmaxf(vb[i].y, 0.0f) + 1e-3)
                  + r2 * ((double)fmaxf(vb[i].z, 0.0f) + 1e-3)
                  + r3 * ((double)fmaxf(vb[i].w, 0.0f) + 1e-3);
        }
#pragma unroll
        for (int i = 0; i < 8; ++i) {
            double s = sv[i];
            s += __shfl_xor(s, 1, 16);
            s += __shfl_xor(s, 2, 16);
            s += __shfl_xor(s, 4, 16);
            s += __shfl_xor(s, 8, 16);
            if (sub == 0) {
                scores[(size_t)b * LL + l0 + rowIn + 16 * (batch * 8 + i)] = s;
                unsigned long long u = (unsigned long long)__double_as_longlong(s);
                ma &= u; mo |= u;
            }
        }
    }

#pragma unroll
    for (int off = 32; off >= 1; off >>= 1) {
        ma &= __shfl_xor(ma, off);
        mo |= __shfl_xor(mo, off);
    }
    if ((threadIdx.x & 63) == 0) { sA2[threadIdx.x >> 6] = ma; sO2[threadIdx.x >> 6] = mo; }
    __syncthreads();
    if (threadIdx.x == 0) {
        atomicAnd(&gAnd[b], sA2[0] & sA2[1] & sA2[2] & sA2[3]);
        atomicOr(&gOr[b], sO2[0] | sO2[1] | sO2[2] | sO2[3]);
    }
}

// ---------------- Kernel 3: privatized histogram (8 blocks/batch, LDS, sparse merge) ----------------
__global__ __launch_bounds__(256) void k_hist(const double* __restrict__ scores,
                                              const unsigned long long* __restrict__ gAnd,
                                              const unsigned long long* __restrict__ gOr,
                                              unsigned int* __restrict__ ghist) {
    int b   = blockIdx.x >> 3;
    int blk = blockIdx.x & 7;
    int tid = threadIdx.x;
    unsigned long long A = gAnd[b], O = gOr[b];
    if (A == O) return;
    int s = win_shift(A, O);

    __shared__ unsigned int lh[4096];
    for (int i = tid; i < 4096; i += 256) lh[i] = 0;
    __syncthreads();

    // 4096 keys per block, 16 per thread, vectorized loads
    const u64x2* sb2 = (const u64x2*)(scores + (size_t)b * LL) + (size_t)blk * 2048;
#pragma unroll
    for (int j = 0; j < 8; ++j) {
        u64x2 p = sb2[tid + j * 256];
        atomicAdd(&lh[(unsigned int)((p.x >> s) & 4095ULL)], 1u);
        atomicAdd(&lh[(unsigned int)((p.y >> s) & 4095ULL)], 1u);
    }
    __syncthreads();

    // sparse merge: one global atomic per non-zero bin (spread addresses)
    unsigned int* gh = ghist + b * 4096;
    for (int i = tid; i < 4096; i += 256) {
        unsigned int c = lh[i];
        if (c) atomicAdd(&gh[i], c);
    }
}

// ---- shared: suffix-scan the 4096-bin histogram -> cutoff bin cb + within-bin rank rp ----
__device__ __forceinline__ void find_cut(const unsigned int* __restrict__ hb, int r, int tid,
                                         unsigned int* sfx, unsigned int* sW,
                                         int* s_cb, int* s_rp) {
    unsigned int h[16], sl[16];
#pragma unroll
    for (int j = 0; j < 16; ++j) h[j] = hb[tid * 16 + j];
    unsigned int run = 0;
#pragma unroll
    for (int j = 15; j >= 0; --j) { run += h[j]; sl[j] = run; }
    unsigned int tot = run, vv = tot;
    int lane = tid & 63;
#pragma unroll
    for (int off = 1; off < 64; off <<= 1) {
        unsigned int t = __shfl_down(vv, off);
        if (lane + off < 64) vv += t;
    }
    if (lane == 0) sW[tid >> 6] = vv;
    __syncthreads();
    unsigned int add = 0;
    int w = tid >> 6;
#pragma unroll
    for (int ww = 0; ww < 4; ++ww) if (ww > w) add += sW[ww];
    unsigned int above = (vv + add) - tot;
#pragma unroll
    for (int j = 0; j < 16; ++j) sfx[tid * 16 + j] = above + sl[j];
    __syncthreads();
#pragma unroll
    for (int j = 0; j < 16; ++j) {
        int d = tid * 16 + j;
        unsigned int S  = sfx[d];
        unsigned int Sn = (d == 4095) ? 0u : sfx[d + 1];
        if (S > (unsigned int)r && Sn <= (unsigned int)r) { *s_cb = d; *s_rp = r - (int)Sn; }
    }
    __syncthreads();
}

// ---------------- Kernel 4: parallel classify+gather (1024 blocks; 256 keys each) ----------------
__global__ __launch_bounds__(256) void k_gather(const double* __restrict__ scores,
                                                const unsigned long long* __restrict__ gAnd,
                                                const unsigned long long* __restrict__ gOr,
                                                const unsigned int* __restrict__ ghist,
                                                const int* __restrict__ topk_p,
                                                unsigned int* __restrict__ eqCnt,
                                                unsigned long long* __restrict__ eqKey,
                                                unsigned int* __restrict__ eqIdx,
                                                const float* __restrict__ v,
                                                float* __restrict__ out) {
    int b   = blockIdx.x >> 7;
    int blk = blockIdx.x & 127;
    int tid = threadIdx.x;
    unsigned long long A = gAnd[b], O = gOr[b];
    if (A == O) return;                 // all scores equal -> nothing selected
    int s = win_shift(A, O);

    __shared__ unsigned int sfx[4096];
    __shared__ unsigned int sW[4];
    __shared__ int s_cb, s_rp, s_cnt;
    __shared__ int s_idx[MAXSEL];
    if (tid == 0) s_cnt = 0;
    find_cut(ghist + b * 4096, topk_p[0], tid, sfx, sW, &s_cb, &s_rp);
    int cb = s_cb;

    int l = blk * 256 + tid;
    unsigned long long key =
        ((const unsigned long long*)(scores + (size_t)b * LL))[l];
    int digit = (int)((key >> s) & 4095ULL);
    if (digit > cb) {
        int sl = atomicAdd(&s_cnt, 1);
        if (sl < MAXSEL) s_idx[sl] = l;
    } else if (digit == cb) {
        unsigned int slot = atomicAdd(&eqCnt[b], 1u);
        if (slot < ECAP) {
            eqKey[(size_t)b * ECAP + slot] = key;
            eqIdx[(size_t)b * ECAP + slot] = (unsigned int)l;
        }
    }
    __syncthreads();
    int cnt = s_cnt < MAXSEL ? s_cnt : MAXSEL;
    int g = tid >> 4, lane16 = tid & 15;
    for (int r2 = g; r2 < cnt; r2 += 16) {
        size_t rowOff = ((size_t)b * LL + s_idx[r2]) * DD;
        ((f4*)(out + rowOff))[lane16] = ((const f4*)(v + rowOff))[lane16];
    }
}

// ---------------- Kernel 5: exact kappa among eq-bin keys + their gather ----------------
__global__ __launch_bounds__(256) void k_final(const double* __restrict__ scores,
                                               const unsigned long long* __restrict__ gAnd,
                                               const unsigned long long* __restrict__ gOr,
                                               const unsigned int* __restrict__ ghist,
                                               const int* __restrict__ topk_p,
                                               const unsigned int* __restrict__ eqCnt,
                                               const unsigned long long* __restrict__ eqKey,
                                               const unsigned int* __restrict__ eqIdx,
                                               const float* __restrict__ v,
                                               float* __restrict__ out) {
    int b = blockIdx.x, tid = threadIdx.x;
    unsigned long long A = gAnd[b], O = gOr[b];
    if (A == O) return;

    __shared__ unsigned int sfx[4096];
    __shared__ unsigned int sW[4];
    __shared__ int s_cb, s_rp, s_cnt;
    __shared__ int s_idx[MAXSEL];
    __shared__ unsigned long long eqL[ECAP];
    __shared__ unsigned long long sKappa;

    unsigned int nc = eqCnt[b];

    if (nc <= ECAP) {
        find_cut(ghist + b * 4096, topk_p[0], tid, sfx, sW, &s_cb, &s_rp);
        int rp = s_rp;

        for (unsigned int i = tid; i < nc; i += 256)
            eqL[i] = eqKey[(size_t)b * ECAP + i];
        __syncthreads();

        // kappa = rp-th largest (0-based) among eq keys (duplicates handled)
        for (unsigned int i = tid; i < nc; i += 256) {
            unsigned long long ki = eqL[i];
            int cg = 0, ce = 0;
            for (unsigned int j = 0; j < nc; ++j) {
                unsigned long long kj = eqL[j];
                cg += (kj > ki);
                ce += (kj == ki);
            }
            if (cg <= rp && rp < cg + ce) sKappa = ki;
        }
        __syncthreads();
        unsigned long long kap = sKappa;
        if (tid == 0) s_cnt = 0;
        __syncthreads();
        for (unsigned int i = tid; i < nc; i += 256) {
            if (eqL[i] > kap) {
                int sl = atomicAdd(&s_cnt, 1);
                if (sl < MAXSEL) s_idx[sl] = (int)eqIdx[(size_t)b * ECAP + i];
            }
        }
        __syncthreads();
    } else {
        // correctness net (eq overflow — not expected): streaming 8-pass radix
        __shared__ unsigned int h2[256];
        __shared__ unsigned long long pfx;
        __shared__ int rr;
        if (tid == 0) { pfx = 0ULL; rr = topk_p[0]; }
        __syncthreads();
        const unsigned long long* sb =
            (const unsigned long long*)(scores + (size_t)b * LL);
        for (int shift = 56; shift >= 0; shift -= 8) {
            h2[tid] = 0;
            __syncthreads();
            unsigned long long hm = (shift == 56) ? 0ULL : (~0ULL << (shift + 8));
            unsigned long long p = pfx;
            for (int l = tid; l < LL; l += 256) {
                unsigned long long kk = sb[l];
                if ((kk & hm) == p)
                    atomicAdd(&h2[(unsigned int)(kk >> shift) & 255u], 1u);
            }
            __syncthreads();
            if (tid == 0) {
                int r = rr; unsigned int cum = 0; int dg = 0;
                for (int i = 255; i >= 0; --i) {
                    unsigned int hh = h2[i];
                    if (cum + hh > (unsigned int)r) { dg = i; rr = r - (int)cum; break; }
                    cum += hh;
                }
                pfx |= ((unsigned long long)dg << shift);
            }
            __syncthreads();
        }
        unsigned long long kap = pfx;
        if (tid == 0) s_cnt = 0;
        __syncthreads();
        for (int l = tid; l < LL; l += 256) {
            if (sb[l] > kap) {
                int sl = atomicAdd(&s_cnt, 1);
                if (sl < MAXSEL) s_idx[sl] = l;
            }
        }
        __syncthreads();
    }

    int cnt = s_cnt < MAXSEL ? s_cnt : MAXSEL;
    int g = tid >> 4, lane16 = tid & 15;
    for (int r2 = g; r2 < cnt; r2 += 16) {
        size_t rowOff = ((size_t)b * LL + s_idx[r2]) * DD;
        ((f4*)(out + rowOff))[lane16] = ((const f4*)(v + rowOff))[lane16];
    }
}

extern "C" void kernel_launch(void* const* d_in, const int* in_sizes, int n_in,
                              void* d_out, int out_size, void* d_ws, size_t ws_size,
                              hipStream_t stream) {
    const float* q = (const float*)d_in[0];
    const float* k = (const float*)d_in[1];
    const float* v = (const float*)d_in[2];
    const int* topk = (const int*)d_in[3];
    float* out = (float*)d_out;

    double* part   = (double*)d_ws;
    double* scores = (double*)((char*)d_ws + 0x40000);
    unsigned int*       ghist = (unsigned int*)((char*)d_ws + 0x240000);
    unsigned long long* gAnd  = (unsigned long long*)((char*)d_ws + 0x260000);
    unsigned long long* gOr   = (unsigned long long*)((char*)d_ws + 0x260040);
    unsigned int*       eqCnt = (unsigned int*)((char*)d_ws + 0x260080);
    unsigned long long* eqKey = (unsigned long long*)((char*)d_ws + 0x260100);
    unsigned int*       eqIdx = (unsigned int*)((char*)d_ws + 0x260100 + (size_t)BB * ECAP * 8);

    k_reduce_q<<<BB * CHUNKS_Q, 256, 0, stream>>>(q, part, out, ghist, gAnd, gOr, eqCnt);
    k_scores<<<BB * (LL / 256), 256, 0, stream>>>(k, part, scores, out, gAnd, gOr);
    k_hist<<<BB * 8, 256, 0, stream>>>(scores, gAnd, gOr, ghist);
    k_gather<<<BB * 128, 256, 0, stream>>>(scores, gAnd, gOr, ghist, topk, eqCnt, eqKey, eqIdx, v, out);
    k_final<<<BB, 256, 0, stream>>>(scores, gAnd, gOr, ghist, topk, eqCnt, eqKey, eqIdx, v, out);
}